// Round 6
// baseline (20.911 us; speedup 1.0000x reference)
//
#include <hip/hip_runtime.h>

// DLGN_VT fused v4 (occupancy + overlap):
//   out[b] = sum_{ijk} g1[b,i] g2[b,j] g3[b,k] V[i,j,k],  g_m = sigmoid(30 * x @ Wm^T)
//   B=4096, D=128, N=32.
//
// 512 blocks x 256 threads; block owns 8 batch rows; 2 blocks/CU (LDS 64.9 KB).
// Stage W(96x128)+x(8x128) -> LDS (stride 132). Then ISSUE all 32 V float4 loads
// (coalesced, disjoint per thread) so they fly under phase 1.
// Phase 1 (t<128): thread=(ks=t>>6 k-half, bp=t&3 -> rows 2bp..2bp+1, fg=(t>>2)&15 ->
//   f in {fg+16*ff}): 2b x 6f register tile = 8 LDS reads / 48 FMA per c. Partials to
//   Pscr (stride 13 pad), combine+sigmoid by all 256 threads -> Gs[8][100].
// Phase 2: thread=(j=t>>3, kchunk=t&7); V in 32 float4 regs, b-loop 8, shfl_xor reduce.
// One dispatch, no atomics, no global scratch.

#define BETA 30.0f

__device__ __forceinline__ float f4c(const float4 v, int c) {
    // compile-time c after full unroll -> folds to a register pick
    return c == 0 ? v.x : (c == 1 ? v.y : (c == 2 ? v.z : v.w));
}

__global__ __launch_bounds__(256, 2) void dlgn_fused4_kernel(
    const float* __restrict__ x,
    const float* __restrict__ W1,
    const float* __restrict__ W2,
    const float* __restrict__ W3,
    const float* __restrict__ V,
    float* __restrict__ out)
{
    __shared__ float Wlds[96 * 132];   // 50688 B
    __shared__ float xlds[8 * 132];    //  4224 B
    __shared__ float Pscr[2][832];     //  6656 B  (64 tiles * 13-pad)
    __shared__ float Gs[8][100];       //  3200 B
    __shared__ float red[4][8];        //   128 B   -> total 64896 B

    const int t  = threadIdx.x;
    const int b0 = blockIdx.x * 8;

    // ---- Stage W rows 0..95 and x rows 96..103 into LDS: 3328 float4 = 13/thread ----
#pragma unroll
    for (int r = 0; r < 13; ++r) {
        const int idx  = r * 256 + t;   // [0,3328)
        const int row  = idx >> 5;
        const int col4 = idx & 31;
        if (row < 96) {
            const float* Wr = (row < 32) ? (W1 + row * 128)
                            : (row < 64) ? (W2 + (row - 32) * 128)
                                         : (W3 + (row - 64) * 128);
            *(float4*)&Wlds[row * 132 + col4 * 4] = ((const float4*)Wr)[col4];
        } else {
            *(float4*)&xlds[(row - 96) * 132 + col4 * 4] =
                ((const float4*)(x + (size_t)(b0 + row - 96) * 128))[col4];
        }
    }
    __syncthreads();

    // ---- Issue V loads now; they complete under phase 1 ----
    const float4* V4 = (const float4*)V;   // V[i][j][k] -> f4 idx i*256 + (j*8+c2) = i*256 + t
    float4 v[32];
#pragma unroll
    for (int i = 0; i < 32; ++i) v[i] = V4[i * 256 + t];

    // ---- Phase 1: gates on waves 0-1. thread -> (ks, bp, fg); 2b x 6f x 16c tile ----
    if (t < 128) {
        const int ks = t >> 6;          // k half: c in [16ks, 16ks+16)
        const int bp = t & 3;           // rows 2bp, 2bp+1
        const int fg = (t >> 2) & 15;   // f = fg + 16*ff
        const float* xr0 = &xlds[(2 * bp + 0) * 132];
        const float* xr1 = &xlds[(2 * bp + 1) * 132];
        const float* wb  = &Wlds[fg * 132];
        float acc0[6] = {0.f,0.f,0.f,0.f,0.f,0.f};
        float acc1[6] = {0.f,0.f,0.f,0.f,0.f,0.f};
        const int cbase = 16 * ks;
#pragma unroll
        for (int cc = 0; cc < 16; ++cc) {
            const int c4 = (cbase + cc) * 4;
            const float4 xv0 = *(const float4*)&xr0[c4];
            const float4 xv1 = *(const float4*)&xr1[c4];
#pragma unroll
            for (int ff = 0; ff < 6; ++ff) {
                const float4 wv = *(const float4*)&wb[ff * 2112 + c4];  // row fg+16ff
                acc0[ff] = fmaf(xv0.x, wv.x, acc0[ff]);
                acc0[ff] = fmaf(xv0.y, wv.y, acc0[ff]);
                acc0[ff] = fmaf(xv0.z, wv.z, acc0[ff]);
                acc0[ff] = fmaf(xv0.w, wv.w, acc0[ff]);
                acc1[ff] = fmaf(xv1.x, wv.x, acc1[ff]);
                acc1[ff] = fmaf(xv1.y, wv.y, acc1[ff]);
                acc1[ff] = fmaf(xv1.z, wv.z, acc1[ff]);
                acc1[ff] = fmaf(xv1.w, wv.w, acc1[ff]);
            }
        }
        float* ps = &Pscr[ks][(bp * 16 + fg) * 13];
#pragma unroll
        for (int ff = 0; ff < 6; ++ff) { ps[ff] = acc0[ff]; ps[6 + ff] = acc1[ff]; }
    }
    __syncthreads();

    // ---- Combine k-halves + sigmoid -> Gs. 768 outputs, 3 per thread ----
#pragma unroll
    for (int r = 0; r < 3; ++r) {
        const int o   = t * 3 + r;          // [0,768)
        const int grp = o / 12;             // bp*16 + fg
        const int sub = o - grp * 12;       // bb*6 + ff
        const float a = Pscr[0][grp * 13 + sub] + Pscr[1][grp * 13 + sub];
        const int bp = grp >> 4, fg = grp & 15;
        const int bb = sub / 6,  ff = sub - 6 * bb;
        Gs[2 * bp + bb][fg + 16 * ff] = 1.0f / (1.0f + __expf(-BETA * a));
    }
    __syncthreads();

    // ---- Phase 2: thread -> (j = t>>3, kchunk c2 = t&7); V already in regs ----
    const int j  = t >> 3;
    const int c2 = t & 7;
    const int w  = t >> 6;
    const int l  = t & 63;

    for (int b = 0; b < 8; ++b) {
        const float4* Gr = (const float4*)&Gs[b][0];
        float4 g1r[8];
#pragma unroll
        for (int c = 0; c < 8; ++c) g1r[c] = Gr[c];             // uniform broadcast
        const float4 g3r = *(const float4*)&Gs[b][64 + c2 * 4]; // 8 addrs, 8 banks
        const float  g2s = Gs[b][32 + j];

        float s = 0.f;
#pragma unroll
        for (int i = 0; i < 32; ++i) {
            float d4 = v[i].x * g3r.x;
            d4 = fmaf(v[i].y, g3r.y, d4);
            d4 = fmaf(v[i].z, g3r.z, d4);
            d4 = fmaf(v[i].w, g3r.w, d4);
            s = fmaf(f4c(g1r[i >> 2], i & 3), d4, s);
        }
        float p = s * g2s;
        p += __shfl_xor(p, 1);
        p += __shfl_xor(p, 2);
        p += __shfl_xor(p, 4);
        p += __shfl_xor(p, 8);
        p += __shfl_xor(p, 16);
        p += __shfl_xor(p, 32);
        if (l == 0) red[w][b] = p;
    }
    __syncthreads();

    if (t < 8) out[b0 + t] = red[0][t] + red[1][t] + red[2][t] + red[3][t];
}

extern "C" void kernel_launch(void* const* d_in, const int* in_sizes, int n_in,
                              void* d_out, int out_size, void* d_ws, size_t ws_size,
                              hipStream_t stream) {
    const float* x  = (const float*)d_in[0];
    const float* W1 = (const float*)d_in[1];
    const float* W2 = (const float*)d_in[2];
    const float* W3 = (const float*)d_in[3];
    const float* V  = (const float*)d_in[4];
    float* out = (float*)d_out;

    dlgn_fused4_kernel<<<dim3(512), dim3(256), 0, stream>>>(x, W1, W2, W3, V, out);
}